// Round 17
// baseline (78.198 us; speedup 1.0000x reference)
//
#include <hip/hip_runtime.h>
#include <hip/hip_bf16.h>

#define HWPIX  16384      // 128*128
#define MTOT   65536      // B*NQ == B*H*W

typedef __attribute__((ext_vector_type(8))) __bf16 bf16x8;
typedef __attribute__((ext_vector_type(4))) __bf16 bf16x4;
typedef __attribute__((ext_vector_type(4))) float  f32x4;

// async global->LDS, 16B per lane; LDS dest must be linear in lane index
#define GLOAD_LDS16(gsrc, ldst)                                                  \
    __builtin_amdgcn_global_load_lds(                                            \
        (const __attribute__((address_space(1))) void*)(gsrc),                   \
        (__attribute__((address_space(3))) void*)(ldst), 16, 0, 0)

// ---------------- weight prep: transpose to [N][K] + bf16 ----------------
__global__ void prep_weights(const float* __restrict__ Woff,
                             const float* __restrict__ Wattn,
                             const float* __restrict__ boff,
                             const float* __restrict__ battn,
                             const float* __restrict__ Wv,
                             const float* __restrict__ Wout,
                             __bf16* __restrict__ W1t,
                             __bf16* __restrict__ Wvt,
                             __bf16* __restrict__ Wot,
                             float* __restrict__ bias1)
{
    int tid = blockIdx.x * blockDim.x + threadIdx.x;
    int stride = gridDim.x * blockDim.x;
    for (int i = tid; i < 96 * 256; i += stride) {
        int n = i >> 8, k = i & 255;
        float v = (n < 64) ? Woff[k * 64 + n] : Wattn[k * 32 + (n - 64)];
        W1t[i] = (__bf16)v;
    }
    for (int i = tid; i < 256 * 256; i += stride) {
        int n = i >> 8, k = i & 255;
        Wvt[i] = (__bf16)Wv[k * 256 + n];
        Wot[i] = (__bf16)Wout[k * 256 + n];
    }
    for (int i = tid; i < 96; i += stride)
        bias1[i] = (i < 64) ? boff[i] : battn[i - 64];
}

// -------- GEMM2: vproj[M,256](bf16) = value[M,256](f32) @ Wvt^T + b_v --------
__global__ __launch_bounds__(512, 4) void gemm256_v(
    const float* __restrict__ A,
    const __bf16* __restrict__ Bt,
    const float* __restrict__ bias,
    __bf16* __restrict__ Out)
{
    __shared__ __bf16 As[2][128 * 32];   // 2 x 8 KB
    __shared__ __bf16 Bs[2][256 * 32];   // 2 x 16 KB

    const int tid  = threadIdx.x;
    const int wave = tid >> 6, lane = tid & 63;
    const int r16  = lane & 15, kq = lane >> 4;
    const long mbase = (long)blockIdx.x * 128;

    const float* ap0 = A + (mbase + (tid >> 3)) * 256 + (tid & 7) * 4;
    const float* ap1 = ap0 + 64 * 256;
    const __bf16* bp0 = Bt + (long)(tid >> 2) * 256 + (tid & 3) * 8;
    const __bf16* bp1 = bp0 + 128 * 256;

    f32x4 acc[16];
#pragma unroll
    for (int n = 0; n < 16; ++n) acc[n] = f32x4{0.f, 0.f, 0.f, 0.f};

    float4 ra0 = *(const float4*)ap0, ra1 = *(const float4*)ap1;
    GLOAD_LDS16(bp0, &Bs[0][tid * 8]);
    GLOAD_LDS16(bp1, &Bs[0][(tid + 512) * 8]);
#define CW256(buf)                                                                \
    {                                                                             \
        bf16x4 o;                                                                 \
        o[0] = (__bf16)ra0.x; o[1] = (__bf16)ra0.y; o[2] = (__bf16)ra0.z; o[3] = (__bf16)ra0.w; \
        *(bf16x4*)&As[buf][tid * 4] = o;                                          \
        o[0] = (__bf16)ra1.x; o[1] = (__bf16)ra1.y; o[2] = (__bf16)ra1.z; o[3] = (__bf16)ra1.w; \
        *(bf16x4*)&As[buf][(tid + 512) * 4] = o;                                  \
    }
    CW256(0);
    __syncthreads();

    for (int t = 0; t < 8; ++t) {
        const int cur = t & 1, nxt = cur ^ 1;
        if (t < 7) {
            const int kt = (t + 1) * 32;
            ra0 = *(const float4*)(ap0 + kt);
            ra1 = *(const float4*)(ap1 + kt);
            GLOAD_LDS16(bp0 + kt, &Bs[nxt][tid * 8]);
            GLOAD_LDS16(bp1 + kt, &Bs[nxt][(tid + 512) * 8]);
        }
        bf16x8 aF = *(const bf16x8*)&As[cur][(wave * 16 + r16) * 32 + kq * 8];
#pragma unroll
        for (int n = 0; n < 16; ++n) {
            bf16x8 bF = *(const bf16x8*)&Bs[cur][(n * 16 + r16) * 32 + kq * 8];
            acc[n] = __builtin_amdgcn_mfma_f32_16x16x32_bf16(aF, bF, acc[n], 0, 0, 0);
        }
        if (t < 7) CW256(nxt);
        __syncthreads();
    }

    long row0 = mbase + wave * 16 + kq * 4;
#pragma unroll
    for (int n = 0; n < 16; ++n) {
        int col = n * 16 + r16;
        float bz = bias[col];
#pragma unroll
        for (int r = 0; r < 4; ++r)
            Out[(row0 + r) * 256 + col] = (__bf16)(acc[n][r] + bz);
    }
}

// per-(q,h) weight-set computation from REGISTER P-slices -> 9 PACKED u32:
// bf16(weight) bits in [31:16], cell index (<16384) in [15:0].
#define MAKESET(E, OFF8_, LG4_, PK)                                               \
    {                                                                             \
        const long q_ = qbase + g * 8 + a + E;                                    \
        const float rx_ = refp[q_ * 2 + 0];                                       \
        const float ry_ = refp[q_ * 2 + 1];                                       \
        float lg0 = (float)LG4_[0], lg1 = (float)LG4_[1];                         \
        float lg2 = (float)LG4_[2], lg3 = (float)LG4_[3];                         \
        float mx = fmaxf(fmaxf(lg0, lg1), fmaxf(lg2, lg3));                       \
        float e0 = __expf(lg0 - mx), e1 = __expf(lg1 - mx);                       \
        float e2 = __expf(lg2 - mx), e3 = __expf(lg3 - mx);                       \
        float inv = 1.f / (e0 + e1 + e2 + e3);                                    \
        float at_[4] = {e0 * inv, e1 * inv, e2 * inv, e3 * inv};                  \
        float wxp[4], wyp[4];                                                     \
        int x0p[4], y0p[4];                                                       \
        int xmin = 127, ymin = 127;                                               \
        _Pragma("unroll")                                                         \
        for (int p = 0; p < 4; ++p) {                                             \
            float ox = (float)OFF8_[2 * p + 0] * (0.1f / 128.f);                  \
            float oy = (float)OFF8_[2 * p + 1] * (0.1f / 128.f);                  \
            float lx = fminf(fmaxf(rx_ + ox, 0.f), 1.f);                          \
            float ly = fminf(fmaxf(ry_ + oy, 0.f), 1.f);                          \
            float ixf = lx * 128.f - 0.5f;                                        \
            float iyf = ly * 128.f - 0.5f;                                        \
            float xf = floorf(ixf), yf = floorf(iyf);                             \
            wxp[p] = ixf - xf; wyp[p] = iyf - yf;                                 \
            x0p[p] = (int)xf;  y0p[p] = (int)yf;                                  \
            xmin = min(xmin, x0p[p]); ymin = min(ymin, y0p[p]);                   \
        }                                                                         \
        float wcg[3][3] = {{0.f,0.f,0.f},{0.f,0.f,0.f},{0.f,0.f,0.f}};            \
        _Pragma("unroll")                                                         \
        for (int p = 0; p < 4; ++p) {                                             \
            int dx = min(x0p[p] - xmin, 1), dy = min(y0p[p] - ymin, 1);           \
            float wx = wxp[p], wy = wyp[p], ap_ = at_[p];                         \
            float xv0 = dx ? 0.f        : 1.f - wx;                               \
            float xv1 = dx ? 1.f - wx   : wx;                                     \
            float xv2 = dx ? wx         : 0.f;                                    \
            float yv0 = (dy ? 0.f      : 1.f - wy) * ap_;                         \
            float yv1 = (dy ? 1.f - wy : wy)       * ap_;                         \
            float yv2 = (dy ? wy       : 0.f)      * ap_;                         \
            wcg[0][0] += yv0 * xv0; wcg[0][1] += yv0 * xv1; wcg[0][2] += yv0 * xv2;\
            wcg[1][0] += yv1 * xv0; wcg[1][1] += yv1 * xv1; wcg[1][2] += yv1 * xv2;\
            wcg[2][0] += yv2 * xv0; wcg[2][1] += yv2 * xv1; wcg[2][2] += yv2 * xv2;\
        }                                                                         \
        _Pragma("unroll")                                                         \
        for (int r = 0; r < 3; ++r)                                               \
            _Pragma("unroll")                                                     \
            for (int s = 0; s < 3; ++s) {                                         \
                int py = ymin + r, px = xmin + s;                                 \
                bool inb = (px >= 0) & (px < 128) & (py >= 0) & (py < 128);       \
                int pyc = min(max(py, 0), 127), pxc = min(max(px, 0), 127);       \
                float wv_ = inb ? wcg[r][s] : 0.f;                                \
                __bf16 bw_ = (__bf16)wv_;                                         \
                unsigned short wb_; __builtin_memcpy(&wb_, &bw_, 2);              \
                PK[r * 3 + s] = ((unsigned)wb_ << 16) | (unsigned)(pyc * 128 + pxc);\
            }                                                                     \
    }

// -------- fused P-GEMM + sampler + out-GEMM: d_out[M,256](f32) ---------------
// Phase 0: P[128][96] = query-tile @ W1t^T + bias1, computed in-block and
//          written to a 24 KB LDS buffer aliased into the TAIL of As
//          (bytes 40960..65536; staging uses As[0..6KB] + Bs[0..8KB]).
// Phase 1: producers load P-slices to registers; packed-shuffle sampling (R16).
// Phase 2: out-GEMM vs staged Wot (R16, with setprio).
__global__ __launch_bounds__(512, 4) void sample_out_fused(
    const float* __restrict__ query,      // [MTOT][256] f32
    const float* __restrict__ refp,       // [MTOT][2]
    const __bf16* __restrict__ vproj,     // [B][HW][256]
    const __bf16* __restrict__ W1t,       // [96][256] bf16 pre-transposed
    const float* __restrict__ bias1,      // [96]
    const __bf16* __restrict__ Wot,       // [256][256] bf16 pre-transposed
    const float* __restrict__ bias,       // [256]
    float* __restrict__ Out)
{
    __shared__ __bf16 As[128 * 256];   // 64 KB (sampling tile; aliased in ph 0)
    __shared__ __bf16 Bs[256 * 32];    // 16 KB (Wot staging; Aq staging in ph 0)

    const int tid = threadIdx.x;
    const int bid = blockIdx.x;
    const int swz = (bid & 7) * 64 + (bid >> 3);      // XCD-aware, 512%8==0
    const long qbase = (long)swz * 128;

    const int wave = tid >> 6, lane = tid & 63;
    const int r16  = lane & 15, kq = lane >> 4;

    __bf16* Pl = (__bf16*)((char*)As + 40960);        // [128][96] bf16, 24 KB

    // ---------- phase 0: P-GEMM (single-buffered, 8 K-steps) ----------
    {
        f32x4 pacc[6];
#pragma unroll
        for (int n = 0; n < 6; ++n) pacc[n] = f32x4{0.f, 0.f, 0.f, 0.f};

        for (int kt = 0; kt < 256; kt += 32) {
            __syncthreads();
            // Aq tile: 128 rows x 32 k, f32->bf16 convert, into Bs region
            {
                const float4* src = (const float4*)(query +
                    (qbase + (tid >> 2)) * 256 + kt + (tid & 3) * 8);
                float4 v0 = src[0], v1 = src[1];
                bf16x8 o;
                o[0] = (__bf16)v0.x; o[1] = (__bf16)v0.y;
                o[2] = (__bf16)v0.z; o[3] = (__bf16)v0.w;
                o[4] = (__bf16)v1.x; o[5] = (__bf16)v1.y;
                o[6] = (__bf16)v1.z; o[7] = (__bf16)v1.w;
                *(bf16x8*)&Bs[tid * 8] = o;
            }
            // W1t tile: 96 rows x 32 k, async into head of As
            if (tid < 384)
                GLOAD_LDS16(W1t + (long)(tid >> 2) * 256 + kt + (tid & 3) * 8,
                            &As[tid * 8]);
            __syncthreads();
            bf16x8 aF = *(const bf16x8*)&Bs[(wave * 16 + r16) * 32 + kq * 8];
#pragma unroll
            for (int n = 0; n < 6; ++n) {
                bf16x8 bF = *(const bf16x8*)&As[(n * 16 + r16) * 32 + kq * 8];
                pacc[n] = __builtin_amdgcn_mfma_f32_16x16x32_bf16(aF, bF, pacc[n], 0, 0, 0);
            }
        }
        // epilogue: +bias1, bf16, into LDS P buffer (tail of As, no overlap)
        int prow = wave * 16 + kq * 4;
#pragma unroll
        for (int n = 0; n < 6; ++n) {
            int col = n * 16 + r16;
            float bz = bias1[col];
#pragma unroll
            for (int r = 0; r < 4; ++r)
                Pl[(prow + r) * 96 + col] = (__bf16)(pacc[n][r] + bz);
        }
    }
    __syncthreads();   // all P writes visible

    // ---------- phase 1: sampling (16 groups x 32 lanes; 8 queries each) ----
    {
        const int g = tid >> 5, l = tid & 31;
        const int h = l >> 2, dg = l & 3;     // consumer roles
        const int a = l >> 3, hh = l & 7;     // producer roles
        const char* vbase = (const char*)(vproj + ((qbase >> 14) << 14) * 256);
        const int chbyte = h * 64 + dg * 16;

        // producer: P-slices from LDS into registers
        bf16x8 off8A = *(const bf16x8*)&Pl[(g * 8 + a + 0) * 96 + hh * 8];
        bf16x4 lg4A  = *(const bf16x4*)&Pl[(g * 8 + a + 0) * 96 + 64 + hh * 4];
        bf16x8 off8B = *(const bf16x8*)&Pl[(g * 8 + a + 4) * 96 + hh * 8];
        bf16x4 lg4B  = *(const bf16x4*)&Pl[(g * 8 + a + 4) * 96 + 64 + hh * 4];

        unsigned pkA[9], pkB[9];
        MAKESET(0, off8A, lg4A, pkA);
        MAKESET(4, off8B, lg4B, pkB);

        __syncthreads();   // P consumed into registers -> As may be overwritten

        // consumer: 8 queries; one shuffle per cell fetches weight+index
#pragma unroll
        for (int i = 0; i < 8; ++i) {
            const int srcl = ((i & 3) << 3) | h;
            int   bo[9];
            float w9[9];
#pragma unroll
            for (int j = 0; j < 9; ++j) {
                unsigned pk = (i < 4) ? (unsigned)__shfl((int)pkA[j], srcl, 32)
                                      : (unsigned)__shfl((int)pkB[j], srcl, 32);
                w9[j] = __uint_as_float(pk & 0xFFFF0000u);
                bo[j] = (int)(pk & 0xFFFFu) * 512 + chbyte;
            }
            // predicated gathers: zero-weight cells issue NO memory request
            uint4 v[9];
#pragma unroll
            for (int j = 0; j < 9; ++j) v[j] = uint4{0u, 0u, 0u, 0u};
#pragma unroll
            for (int j = 0; j < 9; ++j)
                if (w9[j] != 0.f)
                    v[j] = *(const uint4*)(vbase + bo[j]);

            float2 a2[4];
#pragma unroll
            for (int k = 0; k < 4; ++k) a2[k] = float2{0.f, 0.f};
#pragma unroll
            for (int j = 0; j < 9; ++j) {
                float w = w9[j];
#pragma unroll
                for (int k = 0; k < 4; ++k) {
                    unsigned u = (&v[j].x)[k];
                    a2[k].x += w * __uint_as_float(u << 16);
                    a2[k].y += w * __uint_as_float(u & 0xFFFF0000u);
                }
            }
            bf16x8 o;
#pragma unroll
            for (int k = 0; k < 4; ++k) {
                o[2 * k + 0] = (__bf16)a2[k].x;
                o[2 * k + 1] = (__bf16)a2[k].y;
            }
            int ql = g * 8 + i;
            int byte = ql * 512 + ((l * 16) ^ ((ql & 7) << 4));
            *(bf16x8*)((char*)As + byte) = o;
        }
    }

    // ---------- phase 2: GEMM vs Wot ----------
    const int arow = wave * 16 + r16;
    const int abase = arow * 512;
    const int aswz  = (arow & 7) << 4;

    f32x4 acc[16];
#pragma unroll
    for (int n = 0; n < 16; ++n) acc[n] = f32x4{0.f, 0.f, 0.f, 0.f};

    for (int kt = 0; kt < 256; kt += 32) {
        __syncthreads();   // kt=0: sampling writes done; else: prev Bs reads done
        for (int c = tid; c < 1024; c += 512)
            GLOAD_LDS16(Wot + (long)(c >> 2) * 256 + kt + (c & 3) * 8, &Bs[c * 8]);
        __syncthreads();
        bf16x8 aF = *(const bf16x8*)((char*)As + abase + ((kt * 2 + kq * 16) ^ aswz));
        __builtin_amdgcn_s_setprio(1);
#pragma unroll
        for (int n = 0; n < 16; ++n) {
            bf16x8 bF = *(const bf16x8*)&Bs[(n * 16 + r16) * 32 + kq * 8];
            acc[n] = __builtin_amdgcn_mfma_f32_16x16x32_bf16(aF, bF, acc[n], 0, 0, 0);
        }
        __builtin_amdgcn_s_setprio(0);
    }

    long row0 = qbase + wave * 16 + kq * 4;
#pragma unroll
    for (int n = 0; n < 16; ++n) {
        int col = n * 16 + r16;
        float bz = bias[col];
#pragma unroll
        for (int r = 0; r < 4; ++r)
            Out[(row0 + r) * 256 + col] = acc[n][r] + bz;
    }
}

extern "C" void kernel_launch(void* const* d_in, const int* in_sizes, int n_in,
                              void* d_out, int out_size, void* d_ws, size_t ws_size,
                              hipStream_t stream)
{
    const float* query  = (const float*)d_in[0];
    const float* refp   = (const float*)d_in[1];
    const float* value  = (const float*)d_in[2];
    const float* W_off  = (const float*)d_in[3];
    const float* b_off  = (const float*)d_in[4];
    const float* W_attn = (const float*)d_in[5];
    const float* b_attn = (const float*)d_in[6];
    const float* W_v    = (const float*)d_in[7];
    const float* b_v    = (const float*)d_in[8];
    const float* W_out  = (const float*)d_in[9];
    const float* b_out  = (const float*)d_in[10];

    // workspace carve (~32.5 MB total)
    char* w = (char*)d_ws;
    __bf16* vproj   = (__bf16*)w;  w += (size_t)MTOT * 256 * 2;   // 32 MB
    __bf16* W1t     = (__bf16*)w;  w += 96 * 256 * 2;
    __bf16* Wvt     = (__bf16*)w;  w += 256 * 256 * 2;
    __bf16* Wot     = (__bf16*)w;  w += 256 * 256 * 2;
    float*  bias1   = (float*)w;   w += 96 * 4;

    prep_weights<<<120, 256, 0, stream>>>(W_off, W_attn, b_off, b_attn,
                                          W_v, W_out, W1t, Wvt, Wot, bias1);
    gemm256_v<<<MTOT / 128, 512, 0, stream>>>(value, Wvt, b_v, vproj);
    sample_out_fused<<<MTOT / 128, 512, 0, stream>>>(query, refp, vproj,
                                                     W1t, bias1, Wot, b_out,
                                                     (float*)d_out);
}

// Round 18
// 77.499 us; speedup vs baseline: 1.0090x; 1.0090x over previous
//
#include <hip/hip_runtime.h>
#include <hip/hip_bf16.h>

#define HWPIX  16384      // 128*128
#define MTOT   65536      // B*NQ == B*H*W

typedef __attribute__((ext_vector_type(8))) __bf16 bf16x8;
typedef __attribute__((ext_vector_type(4))) __bf16 bf16x4;
typedef __attribute__((ext_vector_type(4))) float  f32x4;

// async global->LDS, 16B per lane; LDS dest must be linear in lane index
#define GLOAD_LDS16(gsrc, ldst)                                                  \
    __builtin_amdgcn_global_load_lds(                                            \
        (const __attribute__((address_space(1))) void*)(gsrc),                   \
        (__attribute__((address_space(3))) void*)(ldst), 16, 0, 0)

// ---------------- weight prep: transpose to [N][K] + bf16 ----------------
__global__ void prep_weights(const float* __restrict__ Woff,
                             const float* __restrict__ Wattn,
                             const float* __restrict__ boff,
                             const float* __restrict__ battn,
                             const float* __restrict__ Wv,
                             const float* __restrict__ Wout,
                             __bf16* __restrict__ W1t,
                             __bf16* __restrict__ Wvt,
                             __bf16* __restrict__ Wot,
                             float* __restrict__ bias1)
{
    int tid = blockIdx.x * blockDim.x + threadIdx.x;
    int stride = gridDim.x * blockDim.x;
    for (int i = tid; i < 96 * 256; i += stride) {
        int n = i >> 8, k = i & 255;
        float v = (n < 64) ? Woff[k * 64 + n] : Wattn[k * 32 + (n - 64)];
        W1t[i] = (__bf16)v;
    }
    for (int i = tid; i < 256 * 256; i += stride) {
        int n = i >> 8, k = i & 255;
        Wvt[i] = (__bf16)Wv[k * 256 + n];
        Wot[i] = (__bf16)Wout[k * 256 + n];
    }
    for (int i = tid; i < 96; i += stride)
        bias1[i] = (i < 64) ? boff[i] : battn[i - 64];
}

// -------- GEMM1: P[M,96](bf16) = query[M,256](f32) @ W1t[96,256]^T + bias ----
__global__ __launch_bounds__(256, 4) void gemm96(
    const float* __restrict__ A,
    const __bf16* __restrict__ Bt,
    const float* __restrict__ bias,
    __bf16* __restrict__ P)
{
    constexpr int NF = 6;
    __shared__ __bf16 As[2][128 * 32];   // 2 x 8 KB
    __shared__ __bf16 Bs[2][96 * 32];    // 2 x 6 KB

    const int tid  = threadIdx.x;
    const int wave = tid >> 6, lane = tid & 63;
    const int r16  = lane & 15, kq = lane >> 4;
    const long mbase = (long)blockIdx.x * 128;

    const float* ap0 = A + (mbase + ((tid + 0 * 256) >> 3)) * 256 + (tid & 7) * 4;
    const float* ap1 = A + (mbase + ((tid + 1 * 256) >> 3)) * 256 + (tid & 7) * 4;
    const float* ap2 = A + (mbase + ((tid + 2 * 256) >> 3)) * 256 + (tid & 7) * 4;
    const float* ap3 = A + (mbase + ((tid + 3 * 256) >> 3)) * 256 + (tid & 7) * 4;
    const __bf16* bp0 = Bt + (long)(tid >> 2) * 256 + (tid & 3) * 8;
    const __bf16* bp1 = Bt + (long)((tid + 256) >> 2) * 256 + (tid & 3) * 8;

    f32x4 acc[2][NF];
#pragma unroll
    for (int m = 0; m < 2; ++m)
#pragma unroll
        for (int n = 0; n < NF; ++n) acc[m][n] = f32x4{0.f, 0.f, 0.f, 0.f};

    float4 ra0 = *(const float4*)ap0, ra1 = *(const float4*)ap1;
    float4 ra2 = *(const float4*)ap2, ra3 = *(const float4*)ap3;
    GLOAD_LDS16(bp0, &Bs[0][tid * 8]);
    if (tid < 128) GLOAD_LDS16(bp1, &Bs[0][(tid + 256) * 8]);
#define CW96(buf)                                                                 \
    {                                                                             \
        bf16x4 o;                                                                 \
        o[0] = (__bf16)ra0.x; o[1] = (__bf16)ra0.y; o[2] = (__bf16)ra0.z; o[3] = (__bf16)ra0.w; \
        *(bf16x4*)&As[buf][(tid + 0 * 256) * 4] = o;                              \
        o[0] = (__bf16)ra1.x; o[1] = (__bf16)ra1.y; o[2] = (__bf16)ra1.z; o[3] = (__bf16)ra1.w; \
        *(bf16x4*)&As[buf][(tid + 1 * 256) * 4] = o;                              \
        o[0] = (__bf16)ra2.x; o[1] = (__bf16)ra2.y; o[2] = (__bf16)ra2.z; o[3] = (__bf16)ra2.w; \
        *(bf16x4*)&As[buf][(tid + 2 * 256) * 4] = o;                              \
        o[0] = (__bf16)ra3.x; o[1] = (__bf16)ra3.y; o[2] = (__bf16)ra3.z; o[3] = (__bf16)ra3.w; \
        *(bf16x4*)&As[buf][(tid + 3 * 256) * 4] = o;                              \
    }
    CW96(0);
    __syncthreads();

    for (int t = 0; t < 8; ++t) {
        const int cur = t & 1, nxt = cur ^ 1;
        if (t < 7) {
            const int kt = (t + 1) * 32;
            ra0 = *(const float4*)(ap0 + kt);
            ra1 = *(const float4*)(ap1 + kt);
            ra2 = *(const float4*)(ap2 + kt);
            ra3 = *(const float4*)(ap3 + kt);
            GLOAD_LDS16(bp0 + kt, &Bs[nxt][tid * 8]);
            if (tid < 128) GLOAD_LDS16(bp1 + kt, &Bs[nxt][(tid + 256) * 8]);
        }
        bf16x8 aF0 = *(const bf16x8*)&As[cur][(wave * 32 + r16) * 32 + kq * 8];
        bf16x8 aF1 = *(const bf16x8*)&As[cur][(wave * 32 + 16 + r16) * 32 + kq * 8];
#pragma unroll
        for (int n = 0; n < NF; ++n) {
            bf16x8 bF = *(const bf16x8*)&Bs[cur][(n * 16 + r16) * 32 + kq * 8];
            acc[0][n] = __builtin_amdgcn_mfma_f32_16x16x32_bf16(aF0, bF, acc[0][n], 0, 0, 0);
            acc[1][n] = __builtin_amdgcn_mfma_f32_16x16x32_bf16(aF1, bF, acc[1][n], 0, 0, 0);
        }
        if (t < 7) CW96(nxt);
        __syncthreads();
    }

#pragma unroll
    for (int m = 0; m < 2; ++m) {
        long row0 = mbase + wave * 32 + m * 16 + kq * 4;
#pragma unroll
        for (int n = 0; n < NF; ++n) {
            int col = n * 16 + r16;
            float bz = bias[col];
#pragma unroll
            for (int r = 0; r < 4; ++r)
                P[(row0 + r) * 96 + col] = (__bf16)(acc[m][n][r] + bz);
        }
    }
}

// -------- GEMM2: vproj[M,256](bf16) = value[M,256](f32) @ Wvt^T + b_v --------
__global__ __launch_bounds__(512, 4) void gemm256_v(
    const float* __restrict__ A,
    const __bf16* __restrict__ Bt,
    const float* __restrict__ bias,
    __bf16* __restrict__ Out)
{
    __shared__ __bf16 As[2][128 * 32];   // 2 x 8 KB
    __shared__ __bf16 Bs[2][256 * 32];   // 2 x 16 KB

    const int tid  = threadIdx.x;
    const int wave = tid >> 6, lane = tid & 63;
    const int r16  = lane & 15, kq = lane >> 4;
    const long mbase = (long)blockIdx.x * 128;

    const float* ap0 = A + (mbase + (tid >> 3)) * 256 + (tid & 7) * 4;
    const float* ap1 = ap0 + 64 * 256;
    const __bf16* bp0 = Bt + (long)(tid >> 2) * 256 + (tid & 3) * 8;
    const __bf16* bp1 = bp0 + 128 * 256;

    f32x4 acc[16];
#pragma unroll
    for (int n = 0; n < 16; ++n) acc[n] = f32x4{0.f, 0.f, 0.f, 0.f};

    float4 ra0 = *(const float4*)ap0, ra1 = *(const float4*)ap1;
    GLOAD_LDS16(bp0, &Bs[0][tid * 8]);
    GLOAD_LDS16(bp1, &Bs[0][(tid + 512) * 8]);
#define CW256(buf)                                                                \
    {                                                                             \
        bf16x4 o;                                                                 \
        o[0] = (__bf16)ra0.x; o[1] = (__bf16)ra0.y; o[2] = (__bf16)ra0.z; o[3] = (__bf16)ra0.w; \
        *(bf16x4*)&As[buf][tid * 4] = o;                                          \
        o[0] = (__bf16)ra1.x; o[1] = (__bf16)ra1.y; o[2] = (__bf16)ra1.z; o[3] = (__bf16)ra1.w; \
        *(bf16x4*)&As[buf][(tid + 512) * 4] = o;                                  \
    }
    CW256(0);
    __syncthreads();

    for (int t = 0; t < 8; ++t) {
        const int cur = t & 1, nxt = cur ^ 1;
        if (t < 7) {
            const int kt = (t + 1) * 32;
            ra0 = *(const float4*)(ap0 + kt);
            ra1 = *(const float4*)(ap1 + kt);
            GLOAD_LDS16(bp0 + kt, &Bs[nxt][tid * 8]);
            GLOAD_LDS16(bp1 + kt, &Bs[nxt][(tid + 512) * 8]);
        }
        bf16x8 aF = *(const bf16x8*)&As[cur][(wave * 16 + r16) * 32 + kq * 8];
#pragma unroll
        for (int n = 0; n < 16; ++n) {
            bf16x8 bF = *(const bf16x8*)&Bs[cur][(n * 16 + r16) * 32 + kq * 8];
            acc[n] = __builtin_amdgcn_mfma_f32_16x16x32_bf16(aF, bF, acc[n], 0, 0, 0);
        }
        if (t < 7) CW256(nxt);
        __syncthreads();
    }

    long row0 = mbase + wave * 16 + kq * 4;
#pragma unroll
    for (int n = 0; n < 16; ++n) {
        int col = n * 16 + r16;
        float bz = bias[col];
#pragma unroll
        for (int r = 0; r < 4; ++r)
            Out[(row0 + r) * 256 + col] = (__bf16)(acc[n][r] + bz);
    }
}

// per-(q,h) weight-set computation -> 9 PACKED u32: bf16(weight) bits in
// [31:16] (unpack = AND + reinterpret), cell index (<16384) in [15:0].
#define MAKESET(E, PK)                                                            \
    {                                                                             \
        const long q_ = qbase + g * 8 + a + E;                                    \
        const __bf16* Pr_ = P + q_ * 96;                                          \
        bf16x8 off8_ = *(const bf16x8*)(Pr_ + hh * 8);                            \
        bf16x4 lg4_  = *(const bf16x4*)(Pr_ + 64 + hh * 4);                       \
        const float rx_ = refp[q_ * 2 + 0];                                       \
        const float ry_ = refp[q_ * 2 + 1];                                       \
        float lg0 = (float)lg4_[0], lg1 = (float)lg4_[1];                         \
        float lg2 = (float)lg4_[2], lg3 = (float)lg4_[3];                         \
        float mx = fmaxf(fmaxf(lg0, lg1), fmaxf(lg2, lg3));                       \
        float e0 = __expf(lg0 - mx), e1 = __expf(lg1 - mx);                       \
        float e2 = __expf(lg2 - mx), e3 = __expf(lg3 - mx);                       \
        float inv = 1.f / (e0 + e1 + e2 + e3);                                    \
        float at_[4] = {e0 * inv, e1 * inv, e2 * inv, e3 * inv};                  \
        float wxp[4], wyp[4];                                                     \
        int x0p[4], y0p[4];                                                       \
        int xmin = 127, ymin = 127;                                               \
        _Pragma("unroll")                                                         \
        for (int p = 0; p < 4; ++p) {                                             \
            float ox = (float)off8_[2 * p + 0] * (0.1f / 128.f);                  \
            float oy = (float)off8_[2 * p + 1] * (0.1f / 128.f);                  \
            float lx = fminf(fmaxf(rx_ + ox, 0.f), 1.f);                          \
            float ly = fminf(fmaxf(ry_ + oy, 0.f), 1.f);                          \
            float ixf = lx * 128.f - 0.5f;                                        \
            float iyf = ly * 128.f - 0.5f;                                        \
            float xf = floorf(ixf), yf = floorf(iyf);                             \
            wxp[p] = ixf - xf; wyp[p] = iyf - yf;                                 \
            x0p[p] = (int)xf;  y0p[p] = (int)yf;                                  \
            xmin = min(xmin, x0p[p]); ymin = min(ymin, y0p[p]);                   \
        }                                                                         \
        float wcg[3][3] = {{0.f,0.f,0.f},{0.f,0.f,0.f},{0.f,0.f,0.f}};            \
        _Pragma("unroll")                                                         \
        for (int p = 0; p < 4; ++p) {                                             \
            int dx = min(x0p[p] - xmin, 1), dy = min(y0p[p] - ymin, 1);           \
            float wx = wxp[p], wy = wyp[p], ap_ = at_[p];                         \
            float xv0 = dx ? 0.f        : 1.f - wx;                               \
            float xv1 = dx ? 1.f - wx   : wx;                                     \
            float xv2 = dx ? wx         : 0.f;                                    \
            float yv0 = (dy ? 0.f      : 1.f - wy) * ap_;                         \
            float yv1 = (dy ? 1.f - wy : wy)       * ap_;                         \
            float yv2 = (dy ? wy       : 0.f)      * ap_;                         \
            wcg[0][0] += yv0 * xv0; wcg[0][1] += yv0 * xv1; wcg[0][2] += yv0 * xv2;\
            wcg[1][0] += yv1 * xv0; wcg[1][1] += yv1 * xv1; wcg[1][2] += yv1 * xv2;\
            wcg[2][0] += yv2 * xv0; wcg[2][1] += yv2 * xv1; wcg[2][2] += yv2 * xv2;\
        }                                                                         \
        _Pragma("unroll")                                                         \
        for (int r = 0; r < 3; ++r)                                               \
            _Pragma("unroll")                                                     \
            for (int s = 0; s < 3; ++s) {                                         \
                int py = ymin + r, px = xmin + s;                                 \
                bool inb = (px >= 0) & (px < 128) & (py >= 0) & (py < 128);       \
                int pyc = min(max(py, 0), 127), pxc = min(max(px, 0), 127);       \
                float wv_ = inb ? wcg[r][s] : 0.f;                                \
                __bf16 bw_ = (__bf16)wv_;                                         \
                unsigned short wb_; __builtin_memcpy(&wb_, &bw_, 2);              \
                PK[r * 3 + s] = ((unsigned)wb_ << 16) | (unsigned)(pyc * 128 + pxc);\
            }                                                                     \
    }

// -------- fused sampler + GEMM3: d_out[M,256](f32) ---------------------------
// Best-measured structure (R16): 128 q/block, producer/consumer weight dedup,
// packed single-shuffle, predicated 3x3-cell gather, setprio'd MFMA cluster.
__global__ __launch_bounds__(512, 4) void sample_out_fused(
    const __bf16* __restrict__ P,         // [MTOT][96] bf16
    const float* __restrict__ refp,       // [MTOT][2]
    const __bf16* __restrict__ vproj,     // [B][HW][256]
    const __bf16* __restrict__ Wot,       // [256][256] bf16 pre-transposed
    const float* __restrict__ bias,
    float* __restrict__ Out)
{
    __shared__ __bf16 As[128 * 256];   // 64 KB, rows XOR-swizzled by (row&7)<<4
    __shared__ __bf16 Bs[256 * 32];    // 16 KB

    const int tid = threadIdx.x;
    const int bid = blockIdx.x;
    const int swz = (bid & 7) * 64 + (bid >> 3);      // XCD-aware, 512%8==0
    const long qbase = (long)swz * 128;

    // ---------- phase 1: sampling (16 groups x 32 lanes; 8 queries each) ----
    {
        const int g = tid >> 5, l = tid & 31;
        const int h = l >> 2, dg = l & 3;     // consumer roles
        const int a = l >> 3, hh = l & 7;     // producer roles
        const char* vbase = (const char*)(vproj + ((qbase >> 14) << 14) * 256);
        const int chbyte = h * 64 + dg * 16;

        // producer: 2 packed weight sets per lane (covers all 64 (q,h))
        unsigned pkA[9], pkB[9];
        MAKESET(0, pkA);
        MAKESET(4, pkB);

        // consumer: 8 queries; one shuffle per cell fetches weight+index
#pragma unroll
        for (int i = 0; i < 8; ++i) {
            const int srcl = ((i & 3) << 3) | h;
            int   bo[9];
            float w9[9];
#pragma unroll
            for (int j = 0; j < 9; ++j) {
                unsigned pk = (i < 4) ? (unsigned)__shfl((int)pkA[j], srcl, 32)
                                      : (unsigned)__shfl((int)pkB[j], srcl, 32);
                w9[j] = __uint_as_float(pk & 0xFFFF0000u);
                bo[j] = (int)(pk & 0xFFFFu) * 512 + chbyte;
            }
            // predicated gathers: zero-weight cells issue NO memory request
            uint4 v[9];
#pragma unroll
            for (int j = 0; j < 9; ++j) v[j] = uint4{0u, 0u, 0u, 0u};
#pragma unroll
            for (int j = 0; j < 9; ++j)
                if (w9[j] != 0.f)
                    v[j] = *(const uint4*)(vbase + bo[j]);

            float2 a2[4];
#pragma unroll
            for (int k = 0; k < 4; ++k) a2[k] = float2{0.f, 0.f};
#pragma unroll
            for (int j = 0; j < 9; ++j) {
                float w = w9[j];
#pragma unroll
                for (int k = 0; k < 4; ++k) {
                    unsigned u = (&v[j].x)[k];
                    a2[k].x += w * __uint_as_float(u << 16);
                    a2[k].y += w * __uint_as_float(u & 0xFFFF0000u);
                }
            }
            bf16x8 o;
#pragma unroll
            for (int k = 0; k < 4; ++k) {
                o[2 * k + 0] = (__bf16)a2[k].x;
                o[2 * k + 1] = (__bf16)a2[k].y;
            }
            int ql = g * 8 + i;
            int byte = ql * 512 + ((l * 16) ^ ((ql & 7) << 4));
            *(bf16x8*)((char*)As + byte) = o;
        }
    }

    // ---------- phase 2: GEMM vs Wot ----------
    const int wave = tid >> 6, lane = tid & 63;
    const int r16  = lane & 15, kq = lane >> 4;
    const int arow = wave * 16 + r16;
    const int abase = arow * 512;
    const int aswz  = (arow & 7) << 4;

    f32x4 acc[16];
#pragma unroll
    for (int n = 0; n < 16; ++n) acc[n] = f32x4{0.f, 0.f, 0.f, 0.f};

    for (int kt = 0; kt < 256; kt += 32) {
        __syncthreads();   // kt=0: sampling writes done; else: prev Bs reads done
        for (int c = tid; c < 1024; c += 512)
            GLOAD_LDS16(Wot + (long)(c >> 2) * 256 + kt + (c & 3) * 8, &Bs[c * 8]);
        __syncthreads();
        bf16x8 aF = *(const bf16x8*)((char*)As + abase + ((kt * 2 + kq * 16) ^ aswz));
        __builtin_amdgcn_s_setprio(1);
#pragma unroll
        for (int n = 0; n < 16; ++n) {
            bf16x8 bF = *(const bf16x8*)&Bs[(n * 16 + r16) * 32 + kq * 8];
            acc[n] = __builtin_amdgcn_mfma_f32_16x16x32_bf16(aF, bF, acc[n], 0, 0, 0);
        }
        __builtin_amdgcn_s_setprio(0);
    }

    long row0 = qbase + wave * 16 + kq * 4;
#pragma unroll
    for (int n = 0; n < 16; ++n) {
        int col = n * 16 + r16;
        float bz = bias[col];
#pragma unroll
        for (int r = 0; r < 4; ++r)
            Out[(row0 + r) * 256 + col] = acc[n][r] + bz;
    }
}

extern "C" void kernel_launch(void* const* d_in, const int* in_sizes, int n_in,
                              void* d_out, int out_size, void* d_ws, size_t ws_size,
                              hipStream_t stream)
{
    const float* query  = (const float*)d_in[0];
    const float* refp   = (const float*)d_in[1];
    const float* value  = (const float*)d_in[2];
    const float* W_off  = (const float*)d_in[3];
    const float* b_off  = (const float*)d_in[4];
    const float* W_attn = (const float*)d_in[5];
    const float* b_attn = (const float*)d_in[6];
    const float* W_v    = (const float*)d_in[7];
    const float* b_v    = (const float*)d_in[8];
    const float* W_out  = (const float*)d_in[9];
    const float* b_out  = (const float*)d_in[10];

    // workspace carve (~44.5 MB total)
    char* w = (char*)d_ws;
    __bf16* P       = (__bf16*)w;  w += (size_t)MTOT * 96 * 2;    // 12 MB
    __bf16* vproj   = (__bf16*)w;  w += (size_t)MTOT * 256 * 2;   // 32 MB
    __bf16* W1t     = (__bf16*)w;  w += 96 * 256 * 2;
    __bf16* Wvt     = (__bf16*)w;  w += 256 * 256 * 2;
    __bf16* Wot     = (__bf16*)w;  w += 256 * 256 * 2;
    float*  bias1   = (float*)w;   w += 96 * 4;

    prep_weights<<<120, 256, 0, stream>>>(W_off, W_attn, b_off, b_attn,
                                          W_v, W_out, W1t, Wvt, Wot, bias1);
    gemm96<<<MTOT / 128, 256, 0, stream>>>(query, W1t, bias1, P);
    gemm256_v<<<MTOT / 128, 512, 0, stream>>>(value, Wvt, b_v, vproj);
    sample_out_fused<<<MTOT / 128, 512, 0, stream>>>(P, refp, vproj, Wot, b_out,
                                                     (float*)d_out);
}